// Round 17
// baseline (1806.480 us; speedup 1.0000x reference)
//
#include <hip/hip_runtime.h>

#define B 16
#define D 256
#define T 4096
#define NQ 8
#define BINS 1024
#define EPS 0.008f

#define OFF_C  ((size_t)B * D * T)            // quantized elems = 16777216
#define OFF_BW (OFF_C + (size_t)NQ * B * T)   // + codes 524288 -> 17301504
#define OFF_L  (OFF_BW + 1)

typedef __attribute__((ext_vector_type(8))) short short8v;
typedef __attribute__((ext_vector_type(4))) float float4v;

// ---- LDS map (bytes) for rvq_scan (256 threads, 64 tokens) ----
// No B-staging: only A-encode/update scratch + norms. 22400 B -> LDS-unconstrained.
#define RESF   0        // f32[16*257] = 16448 (A-encode staging + update rows)
#define IDXS   16448    // i32[64]  -> 16704
#define FLAGS  16704    // i32[64]  -> 16960
#define G1L    16960    // f32[64]  -> 17216
#define RSTG   17216    // f32[256] -> 18240
#define REDW   18240    // f64[4]   -> 18272
#define REDIW  18272    // i32[4]   -> 18288
#define NORMS  18304    // f32[1024] -> 22400
#define SMTOT  22400

__device__ __forceinline__ unsigned short f2bf(float f) {
    unsigned u = __float_as_uint(f);
    unsigned r = (u + 0x7fffu + ((u >> 16) & 1u)) >> 16;   // RNE
    return (unsigned short)r;
}
__device__ __forceinline__ float bf2f(unsigned short h) {
    return __uint_as_float(((unsigned)h) << 16);
}

// ---------------- codebook norms: f64 (exact fallback) + f32 (scan) ----------------
__global__ __launch_bounds__(256) void cbnorm_kernel(const float* __restrict__ cb,
                                                     double* __restrict__ cbn,
                                                     float* __restrict__ cbnf)
{
    const int wave = threadIdx.x >> 6;
    const int lane = threadIdx.x & 63;
    const int bin = blockIdx.x * 4 + wave;          // 0..8191 (q*1024+k)
    const float4 v = *(const float4*)&cb[(size_t)bin * D + lane * 4];
    double a = (double)v.x * v.x + (double)v.y * v.y
             + (double)v.z * v.z + (double)v.w * v.w;
    #pragma unroll
    for (int off = 32; off >= 1; off >>= 1)
        a += __shfl_xor(a, off, 64);
    if (lane == 0) { cbn[bin] = a; cbnf[bin] = (float)a; }
}

// ---------------- prep: codebook -> bf16 hi/lo planes in MFMA-B-fragment order ----
// frag c = q*512 + ntg*8 + ks ; lane l, j -> B[k=ks*32+(l>>4)*8+j][n=ntg*16+(l&15)]
__global__ __launch_bounds__(256) void prep_bfrag(const float* __restrict__ cb,
                                                  unsigned short* __restrict__ bfh,
                                                  unsigned short* __restrict__ bfl)
{
    const int c = blockIdx.x * 4 + (threadIdx.x >> 6);   // 0..4095
    const int lane = threadIdx.x & 63;
    const int q = c >> 9, ntg = (c >> 3) & 63, ks = c & 7;
    const float* src = cb + ((size_t)q * BINS + ntg * 16 + (lane & 15)) * D
                         + ks * 32 + (lane >> 4) * 8;
    short8v h, l;
    #pragma unroll
    for (int j = 0; j < 8; ++j) {
        const float v = src[j];
        const unsigned short hh = f2bf(v);
        h[j] = (short)hh;
        l[j] = (short)f2bf(v - bf2f(hh));
    }
    const size_t off = ((size_t)c * 64 + lane) * 8;
    *(short8v*)(bfh + off) = h;
    *(short8v*)(bfl + off) = l;
}

// ---------------- per-stage scan+update (one launch per q) ----------------
// 256 threads, 64 tokens/block, 4 waves; wave w owns tokens w*16..w*16+15 and
// scans ALL 1024 bins in 64 groups of 16. B-fragments stream global->VGPR
// (L2-resident, lane-contiguous): NO LDS staging, NO barriers in the scan.
// Accumulation order bit-identical to the validated R12 kernel.
__global__ __launch_bounds__(256, 4) void rvq_scan(
    const float* __restrict__ rsrc, float* __restrict__ rdst,
    const float* __restrict__ cb,
    const double* __restrict__ cbn, const float* __restrict__ cbnf,
    const unsigned short* __restrict__ bfh, const unsigned short* __restrict__ bfl,
    float* __restrict__ out, double* __restrict__ lpart, int q)
{
    __shared__ __align__(16) char smem[SMTOT];
    float*  resf   = (float*)(smem + RESF);   // also: rows[16][257] in update phase
    int*    idxsL  = (int*)(smem + IDXS);
    int*    flagsL = (int*)(smem + FLAGS);
    float*  g1L    = (float*)(smem + G1L);
    float*  rstage = (float*)(smem + RSTG);
    float*  normsp = (float*)(smem + NORMS);
    double* redw   = (double*)(smem + REDW);
    int*    rediw  = (int*)(smem + REDIW);

    const int tid  = threadIdx.x;
    const int bid  = blockIdx.x;
    const int b    = bid >> 6;            // T/64 = 64 tiles per batch
    const int t0   = (bid & 63) * 64;
    const int w    = tid >> 6;            // 0..3
    const int lane = tid & 63;
    const int col  = lane & 15;
    const int rgrp = lane >> 4;
    const int rot  = (bid * 5) & 63;      // per-block bin-group rotation (L2 spread)

    const float* rs = rsrc + (size_t)b * D * T + t0;
    float*       rd = rdst + (size_t)b * D * T + t0;

    // ---- 0. norms
    for (int i = tid; i < BINS; i += 256) normsp[i] = cbnf[q * BINS + i];

    // ---- 1. residual -> A-fragments, 4 chunks of 16 tokens through small LDS
    short8v Ah[8], Al[8];
    #pragma unroll 1
    for (int ch = 0; ch < 4; ++ch) {
        #pragma unroll
        for (int it = 0; it < 4; ++it) {
            const int tk4 = (tid & 3) * 4;
            const int d   = it * 64 + (tid >> 2);
            const float4 v = *(const float4*)&rs[(size_t)d * T + ch * 16 + tk4];
            resf[(tk4 + 0) * 257 + d] = v.x;
            resf[(tk4 + 1) * 257 + d] = v.y;
            resf[(tk4 + 2) * 257 + d] = v.z;
            resf[(tk4 + 3) * 257 + d] = v.w;
        }
        __syncthreads();
        if (w == ch) {
            #pragma unroll
            for (int ks = 0; ks < 8; ++ks) {
                short8v h, l;
                #pragma unroll
                for (int j = 0; j < 8; ++j) {
                    const float v = resf[col * 257 + ks * 32 + rgrp * 8 + j];
                    const unsigned short hh = f2bf(v);
                    h[j] = (short)hh;
                    l[j] = (short)f2bf(v - bf2f(hh));
                }
                Ah[ks] = h; Al[ks] = l;
            }
        }
        __syncthreads();
    }

    // ---- 2. scan: 64 groups x 16 bins, B streamed global->VGPR, barrier-free.
    float bv1[4], bv2[4]; int bi1[4];
    #pragma unroll
    for (int s = 0; s < 4; ++s) { bv1[s] = 3.4e38f; bv2[s] = 3.4e38f; bi1[s] = 0; }

    const unsigned short* bqh = bfh + (size_t)q * 512 * 512 + lane * 8;
    const unsigned short* bql = bfl + (size_t)q * 512 * 512 + lane * 8;

    #pragma unroll 1
    for (int nt = 0; nt < 64; ++nt) {
        const int ntr = (nt + rot) & 63;
        const unsigned short* ph = bqh + (size_t)ntr * 4096;
        const unsigned short* pl = bql + (size_t)ntr * 4096;
        const float qn = normsp[ntr * 16 + col];

        float4v a0 = {0,0,0,0}, a1 = {0,0,0,0}, a2 = {0,0,0,0}, a3 = {0,0,0,0};

        // 2-ks chunks: 16 live B-VGPRs; acc mapping (ks&3) identical to R12.
        #define KS2(K0, C0, C1) { \
            const short8v h0 = *(const short8v*)(ph + (K0) * 512); \
            const short8v l0 = *(const short8v*)(pl + (K0) * 512); \
            const short8v h1 = *(const short8v*)(ph + ((K0) + 1) * 512); \
            const short8v l1 = *(const short8v*)(pl + ((K0) + 1) * 512); \
            __builtin_amdgcn_s_setprio(1); \
            C0 = __builtin_amdgcn_mfma_f32_16x16x32_bf16(Al[(K0)],     h0, C0, 0, 0, 0); \
            C0 = __builtin_amdgcn_mfma_f32_16x16x32_bf16(Ah[(K0)],     l0, C0, 0, 0, 0); \
            C0 = __builtin_amdgcn_mfma_f32_16x16x32_bf16(Ah[(K0)],     h0, C0, 0, 0, 0); \
            C1 = __builtin_amdgcn_mfma_f32_16x16x32_bf16(Al[(K0) + 1], h1, C1, 0, 0, 0); \
            C1 = __builtin_amdgcn_mfma_f32_16x16x32_bf16(Ah[(K0) + 1], l1, C1, 0, 0, 0); \
            C1 = __builtin_amdgcn_mfma_f32_16x16x32_bf16(Ah[(K0) + 1], h1, C1, 0, 0, 0); \
            __builtin_amdgcn_s_setprio(0); }
        KS2(0, a0, a1)
        KS2(2, a2, a3)
        KS2(4, a0, a1)
        KS2(6, a2, a3)
        #undef KS2

        const int binb = ntr * 16 + col;
        #pragma unroll
        for (int r = 0; r < 4; ++r) {
            const float s0 = fmaf(-2.0f, (a0[r] + a1[r]) + (a2[r] + a3[r]), qn);
            if (s0 < bv1[r]) { bv2[r] = bv1[r]; bv1[r] = s0; bi1[r] = binb; }
            else if (s0 < bv2[r]) bv2[r] = s0;
        }
    }

    // ---- 3. top-2 merge across 16 cols (within wave), index tiebreak
    #pragma unroll
    for (int off = 1; off <= 8; off <<= 1) {
        #pragma unroll
        for (int sl = 0; sl < 4; ++sl) {
            const float ov1 = __shfl_xor(bv1[sl], off, 64);
            const float ov2 = __shfl_xor(bv2[sl], off, 64);
            const int   oi  = __shfl_xor(bi1[sl], off, 64);
            if (ov1 < bv1[sl] || (ov1 == bv1[sl] && oi < bi1[sl])) {
                bv2[sl] = fminf(bv1[sl], ov2); bv1[sl] = ov1; bi1[sl] = oi;
            } else {
                bv2[sl] = fminf(bv2[sl], ov1);
            }
        }
    }
    if (col == 0) {
        #pragma unroll
        for (int r = 0; r < 4; ++r) {
            const int tk = w * 16 + rgrp * 4 + r;
            idxsL[tk]  = bi1[r];
            g1L[tk]    = bv1[r];
            flagsL[tk] = (bv2[r] - bv1[r] < EPS) ? 1 : 0;
        }
    }
    __syncthreads();

    // ---- 4. exact fallback for near-tie tokens: f32 prefilter + f64 for bins
    //         within g1 + 0.0065 (covers scan err ~2e-3 + rescan err ~1e-3)
    const float* cbq = cb + (size_t)q * BINS * D;
    #pragma unroll 1
    for (int tk2 = 0; tk2 < 64; ++tk2) {
        if (!flagsL[tk2]) continue;                  // uniform branch (LDS)
        rstage[tid] = rs[(size_t)tid * T + tk2];     // tid == d, D == 256
        __syncthreads();
        const float thr = g1L[tk2] + 0.0065f;
        double bb2 = 1e300; int bbi = 0x7fffffff;
        #pragma unroll 1
        for (int jj = 0; jj < 4; ++jj) {
            const int bin = tid + 256 * jj;          // ascending -> lowest-idx kept
            const float* crow = cbq + (size_t)bin * D;
            float f0 = 0.f, f1 = 0.f, f2 = 0.f, f3 = 0.f;
            for (int d = 0; d < D; d += 4) {
                const float4 rv = *(const float4*)&rstage[d];
                const float4 cv = *(const float4*)&crow[d];
                f0 = fmaf(rv.x, cv.x, f0); f1 = fmaf(rv.y, cv.y, f1);
                f2 = fmaf(rv.z, cv.z, f2); f3 = fmaf(rv.w, cv.w, f3);
            }
            const float sf = fmaf(-2.0f, (f0 + f1) + (f2 + f3), normsp[bin]);
            if (sf <= thr) {                         // rare: ~1-3 bins per token
                double a = 0.0;
                for (int d = 0; d < D; d += 4) {
                    const float4 rv = *(const float4*)&rstage[d];
                    const float4 cv = *(const float4*)&crow[d];
                    a = fma((double)rv.x, (double)cv.x, a);
                    a = fma((double)rv.y, (double)cv.y, a);
                    a = fma((double)rv.z, (double)cv.z, a);
                    a = fma((double)rv.w, (double)cv.w, a);
                }
                const double s = fma(-2.0, a, cbn[q * BINS + bin]);
                if (s < bb2) { bb2 = s; bbi = bin; }
            }
        }
        #pragma unroll
        for (int off = 32; off >= 1; off >>= 1) {
            const double ov = __shfl_xor(bb2, off, 64);
            const int   oi  = __shfl_xor(bbi, off, 64);
            if (ov < bb2 || (ov == bb2 && oi < bbi)) { bb2 = ov; bbi = oi; }
        }
        if (lane == 0) { redw[w] = bb2; rediw[w] = bbi; }
        __syncthreads();
        if (tid == 0) {
            double mv = redw[0]; int mi = rediw[0];
            #pragma unroll
            for (int wv = 1; wv < 4; ++wv) {
                const double ov = redw[wv]; const int oi = rediw[wv];
                if (ov < mv || (ov == mv && oi < mi)) { mv = ov; mi = oi; }
            }
            idxsL[tk2] = mi;
        }
        __syncthreads();
    }

    // ---- 5. codes
    if (tid < 64)
        out[OFF_C + (size_t)q * B * T + (size_t)b * T + t0 + tid] = (float)idxsL[tid];

    // ---- 6. faithful f32 straight-through update + loss, 16 tokens at a time
    float* rows = resf;   // [16][257]
    double lacc = 0.0;
    #pragma unroll 1
    for (int g = 0; g < 4; ++g) {
        __syncthreads();                         // prev g's reads done
        {
            const int j = tid >> 4, c = tid & 15;
            const float* crow = cbq + (size_t)idxsL[g * 16 + j] * D + c * 16;
            #pragma unroll
            for (int k2 = 0; k2 < 4; ++k2) {
                const float4 v = *(const float4*)(crow + k2 * 4);
                *(float4*)&rows[j * 257 + c * 16 + k2 * 4] = v;
            }
        }
        __syncthreads();
        #pragma unroll
        for (int it = 0; it < 4; ++it) {
            const int tk4 = (tid & 3) * 4;           // token quad within group
            const int dd_ = it * 64 + (tid >> 2);
            const int tk  = g * 16 + tk4;
            const float4 rv = *(const float4*)&rs[(size_t)dd_ * T + tk];
            const float c0 = rows[(tk4 + 0) * 257 + dd_];
            const float c1 = rows[(tk4 + 1) * 257 + dd_];
            const float c2 = rows[(tk4 + 2) * 257 + dd_];
            const float c3 = rows[(tk4 + 3) * 257 + dd_];
            float4 od;
            float e, qst, dv;
            e = c0 - rv.x; qst = rv.x + e; dv = qst - rv.x;
            lacc = fma((double)dv, (double)dv, lacc); od.x = rv.x - qst;
            e = c1 - rv.y; qst = rv.y + e; dv = qst - rv.y;
            lacc = fma((double)dv, (double)dv, lacc); od.y = rv.y - qst;
            e = c2 - rv.z; qst = rv.z + e; dv = qst - rv.z;
            lacc = fma((double)dv, (double)dv, lacc); od.z = rv.z - qst;
            e = c3 - rv.w; qst = rv.w + e; dv = qst - rv.w;
            lacc = fma((double)dv, (double)dv, lacc); od.w = rv.w - qst;
            *(float4*)&rd[(size_t)dd_ * T + tk] = od;
        }
    }

    // ---- 7. deterministic per-block loss partial (wave shuffle + tiny LDS)
    #pragma unroll
    for (int off = 32; off >= 1; off >>= 1)
        lacc += __shfl_xor(lacc, off, 64);
    __syncthreads();
    if (lane == 0) redw[w] = lacc;
    __syncthreads();
    if (tid == 0)
        lpart[(size_t)q * 1024 + bid] = (redw[0] + redw[1]) + (redw[2] + redw[3]);
}

// ---------------- final: quantized = x - res, in place on out[0:B*D*T) ----------
__global__ __launch_bounds__(256) void final_sub(const float* __restrict__ x,
                                                 float* __restrict__ o)
{
    const size_t i = ((size_t)blockIdx.x * 256 + threadIdx.x) * 4;
    const float4v xv = __builtin_nontemporal_load((const float4v*)(x + i));
    const float4v ov = __builtin_nontemporal_load((const float4v*)(o + i));
    const float4v r = xv - ov;
    __builtin_nontemporal_store(r, (float4v*)(o + i));
}

// ---------------- OLD PATH (R2, known-good) kept as ws-size fallback ----------------
#define OTOK 32
#define ORS 260
__global__ __launch_bounds__(256, 3) void rvq_main_old(
    const float* __restrict__ x, const float* __restrict__ cb,
    const double* __restrict__ cbn, const float* __restrict__ cbnf,
    float* __restrict__ out, double* __restrict__ lpart)
{
    __shared__ float  res[OTOK][ORS];
    __shared__ float  bv1s[OTOK][16];
    __shared__ float  bv2s[OTOK][16];
    __shared__ int    bi1s[OTOK][16];
    __shared__ int    idxs[OTOK];
    __shared__ int    flags[OTOK];
    __shared__ double fbv[256];
    __shared__ int    fbi[256];

    const int tid = threadIdx.x;
    const int bid = blockIdx.x;
    const int b  = bid >> 7;
    const int t0 = (bid & 127) * OTOK;

    const float* xb = x + (size_t)b * D * T + t0;
    #pragma unroll
    for (int it = 0; it < 32; ++it) {
        const int d  = it * 8 + (tid >> 5);
        const int tk = tid & 31;
        res[tk][d] = xb[(size_t)d * T + tk];
    }
    __syncthreads();

    float qreg[32];
    #pragma unroll
    for (int i = 0; i < 32; ++i) qreg[i] = 0.0f;

    const int tg = tid & 15;
    const int bg = tid >> 4;
    const int tku = tid >> 3;
    const int d0u = (tid & 7) * 32;
    double lacc = 0.0;

    for (int q = 0; q < NQ; ++q) {
        const float*  cbq = cb   + (size_t)q * BINS * D;
        const float*  cnf = cbnf + (size_t)q * BINS;
        const double* cnd = cbn  + (size_t)q * BINS;

        float bvA = 3.4e38f, bvA2 = 3.4e38f;  int biA = 0;
        float bvB = 3.4e38f, bvB2 = 3.4e38f;  int biB = 0;

        for (int iter = 0; iter < 8; ++iter) {
            const int binbase = iter * 128 + bg * 8;
            float a0[8], a1[8];
            #pragma unroll
            for (int j = 0; j < 8; ++j) { a0[j] = 0.0f; a1[j] = 0.0f; }
            for (int d = 0; d < D; d += 4) {
                const float4 r0 = *(const float4*)&res[tg][d];
                const float4 r1 = *(const float4*)&res[tg + 16][d];
                #pragma unroll
                for (int j = 0; j < 8; ++j) {
                    const float4 c = *(const float4*)&cbq[(size_t)(binbase + j) * D + d];
                    a0[j] = fmaf(r0.x, c.x, a0[j]); a0[j] = fmaf(r0.y, c.y, a0[j]);
                    a0[j] = fmaf(r0.z, c.z, a0[j]); a0[j] = fmaf(r0.w, c.w, a0[j]);
                    a1[j] = fmaf(r1.x, c.x, a1[j]); a1[j] = fmaf(r1.y, c.y, a1[j]);
                    a1[j] = fmaf(r1.z, c.z, a1[j]); a1[j] = fmaf(r1.w, c.w, a1[j]);
                }
            }
            #pragma unroll
            for (int j = 0; j < 8; ++j) {
                const int bin = binbase + j;
                const float qn = cnf[bin];
                const float s0 = fmaf(-2.0f, a0[j], qn);
                const float s1 = fmaf(-2.0f, a1[j], qn);
                if (s0 < bvA) { bvA2 = bvA; bvA = s0; biA = bin; }
                else if (s0 < bvA2) { bvA2 = s0; }
                if (s1 < bvB) { bvB2 = bvB; bvB = s1; biB = bin; }
                else if (s1 < bvB2) { bvB2 = s1; }
            }
        }
        bv1s[tg][bg]      = bvA;  bv2s[tg][bg]      = bvA2;  bi1s[tg][bg]      = biA;
        bv1s[tg + 16][bg] = bvB;  bv2s[tg + 16][bg] = bvB2;  bi1s[tg + 16][bg] = biB;
        __syncthreads();

        if (tid < OTOK) {
            float g1 = bv1s[tid][0], g2 = bv2s[tid][0];
            int   gi = bi1s[tid][0];
            #pragma unroll
            for (int g = 1; g < 16; ++g) {
                const float v1 = bv1s[tid][g];
                const float v2 = bv2s[tid][g];
                const int   i1 = bi1s[tid][g];
                if (v1 < g1 || (v1 == g1 && i1 < gi)) { g2 = fminf(g1, v2); g1 = v1; gi = i1; }
                else g2 = fminf(g2, v1);
            }
            idxs[tid]  = gi;
            flags[tid] = (g2 - g1 < 0.02f) ? 1 : 0;
        }
        __syncthreads();

        for (int tok = 0; tok < OTOK; ++tok) {
            if (!flags[tok]) continue;
            double bb = 1e300; int bbi = 0;
            #pragma unroll
            for (int jj = 0; jj < 4; ++jj) {
                const int bin = tid + 256 * jj;
                const float* crow = cbq + (size_t)bin * D;
                double a = 0.0;
                for (int d = 0; d < D; d += 4) {
                    const float4 r = *(const float4*)&res[tok][d];
                    const float4 c = *(const float4*)&crow[d];
                    a = fma((double)r.x, (double)c.x, a);
                    a = fma((double)r.y, (double)c.y, a);
                    a = fma((double)r.z, (double)c.z, a);
                    a = fma((double)r.w, (double)c.w, a);
                }
                const double s = fma(-2.0, a, cnd[bin]);
                if (s < bb) { bb = s; bbi = bin; }
            }
            fbv[tid] = bb; fbi[tid] = bbi;
            __syncthreads();
            for (int s2 = 128; s2 >= 1; s2 >>= 1) {
                if (tid < s2) {
                    const double ov = fbv[tid + s2]; const int oi = fbi[tid + s2];
                    const double mv = fbv[tid];      const int mi = fbi[tid];
                    if (ov < mv || (ov == mv && oi < mi)) { fbv[tid] = ov; fbi[tid] = oi; }
                }
                __syncthreads();
            }
            if (tid == 0) idxs[tok] = fbi[0];
            __syncthreads();
        }

        if (tid < OTOK)
            out[OFF_C + (size_t)q * B * T + (size_t)b * T + t0 + tid] = (float)idxs[tid];

        const float* crow = cbq + (size_t)idxs[tku] * D;
        #pragma unroll
        for (int i = 0; i < 8; ++i) {
            const int d = d0u + i * 4;
            const float4 qv = *(const float4*)&crow[d];
            float4 r = *(float4*)&res[tku][d];
            float e, qst, dd;
            e = qv.x - r.x; qst = r.x + e; dd = qst - r.x;
            lacc = fma((double)dd, (double)dd, lacc); qreg[i*4+0] += qst; r.x = r.x - qst;
            e = qv.y - r.y; qst = r.y + e; dd = qst - r.y;
            lacc = fma((double)dd, (double)dd, lacc); qreg[i*4+1] += qst; r.y = r.y - qst;
            e = qv.z - r.z; qst = r.z + e; dd = qst - r.z;
            lacc = fma((double)dd, (double)dd, lacc); qreg[i*4+2] += qst; r.z = r.z - qst;
            e = qv.w - r.w; qst = r.w + e; dd = qst - r.w;
            lacc = fma((double)dd, (double)dd, lacc); qreg[i*4+3] += qst; r.w = r.w - qst;
            *(float4*)&res[tku][d] = r;
        }
        __syncthreads();
    }

    #pragma unroll
    for (int i = 0; i < 8; ++i)
        *(float4*)&res[tku][d0u + i * 4] = *(float4*)&qreg[i * 4];
    __syncthreads();
    #pragma unroll
    for (int it = 0; it < 32; ++it) {
        const int d  = it * 8 + (tid >> 5);
        const int tk = tid & 31;
        out[(size_t)b * D * T + (size_t)d * T + t0 + tk] = res[tk][d];
    }

    fbv[tid] = lacc;
    __syncthreads();
    for (int s2 = 128; s2 >= 1; s2 >>= 1) {
        if (tid < s2) fbv[tid] += fbv[tid + s2];
        __syncthreads();
    }
    if (tid == 0) lpart[bid] = fbv[0];
}

// ---------------- finalize: loss mean + bandwidth scalar ----------------
__global__ __launch_bounds__(256) void finalize_kernel(
    const double* __restrict__ lpart, int nblk,
    const int* __restrict__ srp, float* __restrict__ out)
{
    __shared__ double sh[256];
    double a = 0.0;
    for (int i = threadIdx.x; i < nblk; i += 256) a += lpart[i];
    sh[threadIdx.x] = a;
    __syncthreads();
    for (int s = 128; s >= 1; s >>= 1) {
        if (threadIdx.x < s) sh[threadIdx.x] += sh[threadIdx.x + s];
        __syncthreads();
    }
    if (threadIdx.x == 0) {
        out[OFF_L]  = (float)(sh[0] / ((double)NQ * B * T * D));
        out[OFF_BW] = (float)((double)NQ * 10.0 * (double)srp[0] / 1000.0);
    }
}

extern "C" void kernel_launch(void* const* d_in, const int* in_sizes, int n_in,
                              void* d_out, int out_size, void* d_ws, size_t ws_size,
                              hipStream_t stream)
{
    const float* x  = (const float*)d_in[0];
    const float* cb = (const float*)d_in[1];
    const int*   sr = (const int*)d_in[2];
    float* out = (float*)d_out;

    // ws layout: cbn f64[8192] @0 (65536) | cbnf f32[8192] @65536 (32768)
    //            lpart f64[8192] @98304 (65536) | bfh @163840 (4 MiB) | bfl @4358144
    //            total 8552448 B
    double* cbn   = (double*)d_ws;
    float*  cbnf  = (float*)((char*)d_ws + 65536);
    double* lpart = (double*)((char*)d_ws + 98304);
    unsigned short* bfh = (unsigned short*)((char*)d_ws + 163840);
    unsigned short* bfl = (unsigned short*)((char*)d_ws + 4358144);

    hipLaunchKernelGGL(cbnorm_kernel, dim3(NQ * BINS / 4), dim3(256), 0, stream, cb, cbn, cbnf);

    if (ws_size >= (size_t)8552448) {
        hipLaunchKernelGGL(prep_bfrag, dim3(1024), dim3(256), 0, stream, cb, bfh, bfl);
        float* resb = out;   // quantized section doubles as residual buffer
        for (int q = 0; q < NQ; ++q) {
            hipLaunchKernelGGL(rvq_scan, dim3(B * (T / 64)), dim3(256), 0, stream,
                               (q == 0 ? x : (const float*)resb), resb, cb, cbn, cbnf,
                               bfh, bfl, out, lpart, q);
        }
        hipLaunchKernelGGL(final_sub, dim3((B * D * T) / 1024), dim3(256), 0, stream, x, resb);
        hipLaunchKernelGGL(finalize_kernel, dim3(1), dim3(256), 0, stream,
                           lpart, NQ * 1024, sr, out);
    } else {
        hipLaunchKernelGGL(rvq_main_old, dim3(B * (T / OTOK)), dim3(256), 0, stream,
                           x, cb, cbn, cbnf, out, lpart);
        hipLaunchKernelGGL(finalize_kernel, dim3(1), dim3(256), 0, stream,
                           lpart, B * (T / OTOK), sr, out);
    }
}

// Round 18
// 1522.292 us; speedup vs baseline: 1.1867x; 1.1867x over previous
//
#include <hip/hip_runtime.h>

#define B 16
#define D 256
#define T 4096
#define NQ 8
#define BINS 1024
#define EPS 0.008f

#define OFF_C  ((size_t)B * D * T)            // quantized elems = 16777216
#define OFF_BW (OFF_C + (size_t)NQ * B * T)   // + codes 524288 -> 17301504
#define OFF_L  (OFF_BW + 1)

typedef __attribute__((ext_vector_type(8))) short short8v;
typedef __attribute__((ext_vector_type(4))) float float4v;

// ---- LDS map (bytes) for rvq_scan (256 threads, 64 tokens, 4 blocks/CU) ----
#define BBUF   0        // 2 x 16384 double buffer (union RESF/ROWS 16x257x4 = 16448)
#define RESF   0
#define IDXS   32768    // i32[64]   -> 33024
#define FLAGS  33024    // i32[64]   -> 33280
#define G1L    33280    // f32[64]   -> 33536
#define RSTG   33536    // f32[256]  -> 34560
#define NORMS  34560    // f32[1024] -> 38656
#define REDW   38656    // f64[4]    -> 38688
#define REDIW  38688    // i32[4]    -> 38704
#define SMTOT  38704    // x4 = 154816 <= 163840 -> 4 blocks/CU

#define STAGE16(gp, loff) \
  __builtin_amdgcn_global_load_lds( \
      (const __attribute__((address_space(1))) unsigned int*)(gp), \
      (__attribute__((address_space(3))) unsigned int*)(smc + (loff)), 16, 0, 0)

__device__ __forceinline__ unsigned short f2bf(float f) {
    unsigned u = __float_as_uint(f);
    unsigned r = (u + 0x7fffu + ((u >> 16) & 1u)) >> 16;   // RNE
    return (unsigned short)r;
}
__device__ __forceinline__ float bf2f(unsigned short h) {
    return __uint_as_float(((unsigned)h) << 16);
}

// ---------------- codebook norms: f64 (exact fallback) + f32 (scan) ----------------
__global__ __launch_bounds__(256) void cbnorm_kernel(const float* __restrict__ cb,
                                                     double* __restrict__ cbn,
                                                     float* __restrict__ cbnf)
{
    const int wave = threadIdx.x >> 6;
    const int lane = threadIdx.x & 63;
    const int bin = blockIdx.x * 4 + wave;          // 0..8191 (q*1024+k)
    const float4 v = *(const float4*)&cb[(size_t)bin * D + lane * 4];
    double a = (double)v.x * v.x + (double)v.y * v.y
             + (double)v.z * v.z + (double)v.w * v.w;
    #pragma unroll
    for (int off = 32; off >= 1; off >>= 1)
        a += __shfl_xor(a, off, 64);
    if (lane == 0) { cbn[bin] = a; cbnf[bin] = (float)a; }
}

// ---------------- prep: codebook -> bf16 hi/lo planes in MFMA-B-fragment order ----
// frag c = q*512 + ntg*8 + ks ; lane l, j -> B[k=ks*32+(l>>4)*8+j][n=ntg*16+(l&15)]
__global__ __launch_bounds__(256) void prep_bfrag(const float* __restrict__ cb,
                                                  unsigned short* __restrict__ bfh,
                                                  unsigned short* __restrict__ bfl)
{
    const int c = blockIdx.x * 4 + (threadIdx.x >> 6);   // 0..4095
    const int lane = threadIdx.x & 63;
    const int q = c >> 9, ntg = (c >> 3) & 63, ks = c & 7;
    const float* src = cb + ((size_t)q * BINS + ntg * 16 + (lane & 15)) * D
                         + ks * 32 + (lane >> 4) * 8;
    short8v h, l;
    #pragma unroll
    for (int j = 0; j < 8; ++j) {
        const float v = src[j];
        const unsigned short hh = f2bf(v);
        h[j] = (short)hh;
        l[j] = (short)f2bf(v - bf2f(hh));
    }
    const size_t off = ((size_t)c * 64 + lane) * 8;
    *(short8v*)(bfh + off) = h;
    *(short8v*)(bfl + off) = l;
}

// ---------------- per-stage scan+update (one launch per q) ----------------
// 256 threads, 64 tokens/block, 4 waves; wave w owns tokens w*16..w*16+15 and
// scans ALL 1024 bins in 64 steps of 16 bins. A hi/lo in regs; B via LDS
// double buffer, ONE barrier per step (issue-at-top), setprio around MFMA.
__global__ __launch_bounds__(256, 4) void rvq_scan(
    const float* __restrict__ rsrc, float* __restrict__ rdst,
    const float* __restrict__ cb,
    const double* __restrict__ cbn, const float* __restrict__ cbnf,
    const unsigned short* __restrict__ bfh, const unsigned short* __restrict__ bfl,
    float* __restrict__ out, double* __restrict__ lpart, int q)
{
    __shared__ __align__(16) char smem[SMTOT];
    char*   smc    = smem;
    float*  resf   = (float*)(smem + RESF);   // also: rows[16][257] in update phase
    int*    idxsL  = (int*)(smem + IDXS);
    int*    flagsL = (int*)(smem + FLAGS);
    float*  g1L    = (float*)(smem + G1L);
    float*  rstage = (float*)(smem + RSTG);
    float*  normsp = (float*)(smem + NORMS);
    double* redw   = (double*)(smem + REDW);
    int*    rediw  = (int*)(smem + REDIW);

    const int tid  = threadIdx.x;
    const int bid  = blockIdx.x;
    const int b    = bid >> 6;            // T/64 = 64 tiles per batch
    const int t0   = (bid & 63) * 64;
    const int w    = tid >> 6;            // 0..3
    const int lane = tid & 63;
    const int col  = lane & 15;
    const int rgrp = lane >> 4;
    const int rot  = (bid * 5) & 63;      // per-block bin-group rotation (L2 spread)

    const float* rs = rsrc + (size_t)b * D * T + t0;
    float*       rd = rdst + (size_t)b * D * T + t0;

    // ---- 0. norms (doesn't alias resf)
    for (int i = tid; i < BINS; i += 256) normsp[i] = cbnf[q * BINS + i];

    // ---- 1. residual -> A-fragments, 4 chunks of 16 tokens through small LDS
    //        (float4-vectorized staging: 4 iters of 16B vs 16 iters of 4B)
    short8v Ah[8], Al[8];
    #pragma unroll 1
    for (int ch = 0; ch < 4; ++ch) {
        #pragma unroll
        for (int it = 0; it < 4; ++it) {
            const int tk4 = (tid & 3) * 4;
            const int d   = it * 64 + (tid >> 2);
            const float4 v = *(const float4*)&rs[(size_t)d * T + ch * 16 + tk4];
            resf[(tk4 + 0) * 257 + d] = v.x;
            resf[(tk4 + 1) * 257 + d] = v.y;
            resf[(tk4 + 2) * 257 + d] = v.z;
            resf[(tk4 + 3) * 257 + d] = v.w;
        }
        __syncthreads();
        if (w == ch) {
            #pragma unroll
            for (int ks = 0; ks < 8; ++ks) {
                short8v h, l;
                #pragma unroll
                for (int j = 0; j < 8; ++j) {
                    const float v = resf[col * 257 + ks * 32 + rgrp * 8 + j];
                    const unsigned short hh = f2bf(v);
                    h[j] = (short)hh;
                    l[j] = (short)f2bf(v - bf2f(hh));
                }
                Ah[ks] = h; Al[ks] = l;
            }
        }
        __syncthreads();
    }
    // resf dead; BBUF owns the union from here

    // ---- 2. staging setup: wave (plane = w>>1, part = w&1) stages 4 KB per step
    const int plane = w >> 1, part = w & 1;
    const unsigned short* sbase = plane ? bfl : bfh;

    // prologue: issue buf0 loads (bin-group rot)
    {
        const unsigned short* srcp =
            sbase + ((size_t)q * 512 + rot * 8 + part * 4) * 512 + lane * 8;
        const int dstb = plane * 8192 + part * 4096;
        #pragma unroll
        for (int i = 0; i < 4; ++i) STAGE16(srcp + i * 512, dstb + i * 1024);
    }

    // ---- 3. scan loop: 64 steps x 16 bins, ONE barrier per step
    float bv1[4], bv2[4]; int bi1[4];
    #pragma unroll
    for (int s = 0; s < 4; ++s) { bv1[s] = 3.4e38f; bv2[s] = 3.4e38f; bi1[s] = 0; }

    #pragma unroll 1
    for (int nt = 0; nt < 64; ++nt) {
        // only my 4 loads (for buf cur) are outstanding -> exact wait
        asm volatile("s_waitcnt vmcnt(0)" ::: "memory");
        __builtin_amdgcn_s_barrier();     // everyone's loads done AND everyone
        asm volatile("" ::: "memory");    // finished reading buf cur^1 last step

        const int cur = nt & 1;
        // issue next step's loads into buf cur^1 (overlaps with compute below)
        if (nt < 63) {
            const int ntg = (nt + 1 + rot) & 63;
            const unsigned short* srcp =
                sbase + ((size_t)q * 512 + ntg * 8 + part * 4) * 512 + lane * 8;
            const int dstb = (cur ^ 1) * 16384 + plane * 8192 + part * 4096;
            #pragma unroll
            for (int i = 0; i < 4; ++i) STAGE16(srcp + i * 512, dstb + i * 1024);
        }
        asm volatile("" ::: "memory");

        const int ntr = (nt + rot) & 63;
        const char* bb = smc + cur * 16384;
        const float qn = normsp[ntr * 16 + col];

        float4v a0 = {0,0,0,0}, a1 = {0,0,0,0}, a2 = {0,0,0,0}, a3 = {0,0,0,0};
        __builtin_amdgcn_s_setprio(1);
        #pragma unroll
        for (int ks = 0; ks < 8; ++ks) {
            const short8v Bh = *(const short8v*)(bb + ks * 1024 + lane * 16);
            const short8v Bl = *(const short8v*)(bb + 8192 + ks * 1024 + lane * 16);
            float4v& c = (ks & 3) == 0 ? a0 : ((ks & 3) == 1 ? a1 : ((ks & 3) == 2 ? a2 : a3));
            c = __builtin_amdgcn_mfma_f32_16x16x32_bf16(Al[ks], Bh, c, 0, 0, 0);
            c = __builtin_amdgcn_mfma_f32_16x16x32_bf16(Ah[ks], Bl, c, 0, 0, 0);
            c = __builtin_amdgcn_mfma_f32_16x16x32_bf16(Ah[ks], Bh, c, 0, 0, 0);
        }
        __builtin_amdgcn_s_setprio(0);

        const int binb = ntr * 16 + col;
        #pragma unroll
        for (int r = 0; r < 4; ++r) {
            const float s0 = fmaf(-2.0f, (a0[r] + a1[r]) + (a2[r] + a3[r]), qn);
            if (s0 < bv1[r]) { bv2[r] = bv1[r]; bv1[r] = s0; bi1[r] = binb; }
            else if (s0 < bv2[r]) bv2[r] = s0;
        }
    }

    // ---- 4. top-2 merge across 16 cols (within wave), index tiebreak
    #pragma unroll
    for (int off = 1; off <= 8; off <<= 1) {
        #pragma unroll
        for (int sl = 0; sl < 4; ++sl) {
            const float ov1 = __shfl_xor(bv1[sl], off, 64);
            const float ov2 = __shfl_xor(bv2[sl], off, 64);
            const int   oi  = __shfl_xor(bi1[sl], off, 64);
            if (ov1 < bv1[sl] || (ov1 == bv1[sl] && oi < bi1[sl])) {
                bv2[sl] = fminf(bv1[sl], ov2); bv1[sl] = ov1; bi1[sl] = oi;
            } else {
                bv2[sl] = fminf(bv2[sl], ov1);
            }
        }
    }
    if (col == 0) {
        #pragma unroll
        for (int r = 0; r < 4; ++r) {
            const int tk = w * 16 + rgrp * 4 + r;
            idxsL[tk]  = bi1[r];
            g1L[tk]    = bv1[r];
            flagsL[tk] = (bv2[r] - bv1[r] < EPS) ? 1 : 0;
        }
    }
    __syncthreads();

    // ---- 5. exact fallback for near-tie tokens: f32 prefilter + f64 for bins
    //         within g1 + 0.0065 (covers scan err ~2e-3 + rescan err ~1e-3)
    const float* cbq = cb + (size_t)q * BINS * D;
    #pragma unroll 1
    for (int tk2 = 0; tk2 < 64; ++tk2) {
        if (!flagsL[tk2]) continue;                  // uniform branch (LDS)
        rstage[tid] = rs[(size_t)tid * T + tk2];     // tid == d, D == 256
        __syncthreads();
        const float thr = g1L[tk2] + 0.0065f;
        double bb2 = 1e300; int bbi = 0x7fffffff;
        #pragma unroll 1
        for (int jj = 0; jj < 4; ++jj) {
            const int bin = tid + 256 * jj;          // ascending -> lowest-idx kept
            const float* crow = cbq + (size_t)bin * D;
            float f0 = 0.f, f1 = 0.f, f2 = 0.f, f3 = 0.f;
            for (int d = 0; d < D; d += 4) {
                const float4 rv = *(const float4*)&rstage[d];
                const float4 cv = *(const float4*)&crow[d];
                f0 = fmaf(rv.x, cv.x, f0); f1 = fmaf(rv.y, cv.y, f1);
                f2 = fmaf(rv.z, cv.z, f2); f3 = fmaf(rv.w, cv.w, f3);
            }
            const float sf = fmaf(-2.0f, (f0 + f1) + (f2 + f3), normsp[bin]);
            if (sf <= thr) {                         // rare: ~1-3 bins per token
                double a = 0.0;
                for (int d = 0; d < D; d += 4) {
                    const float4 rv = *(const float4*)&rstage[d];
                    const float4 cv = *(const float4*)&crow[d];
                    a = fma((double)rv.x, (double)cv.x, a);
                    a = fma((double)rv.y, (double)cv.y, a);
                    a = fma((double)rv.z, (double)cv.z, a);
                    a = fma((double)rv.w, (double)cv.w, a);
                }
                const double s = fma(-2.0, a, cbn[q * BINS + bin]);
                if (s < bb2) { bb2 = s; bbi = bin; }
            }
        }
        #pragma unroll
        for (int off = 32; off >= 1; off >>= 1) {
            const double ov = __shfl_xor(bb2, off, 64);
            const int   oi  = __shfl_xor(bbi, off, 64);
            if (ov < bb2 || (ov == bb2 && oi < bbi)) { bb2 = ov; bbi = oi; }
        }
        if (lane == 0) { redw[w] = bb2; rediw[w] = bbi; }
        __syncthreads();
        if (tid == 0) {
            double mv = redw[0]; int mi = rediw[0];
            #pragma unroll
            for (int wv = 1; wv < 4; ++wv) {
                const double ov = redw[wv]; const int oi = rediw[wv];
                if (ov < mv || (ov == mv && oi < mi)) { mv = ov; mi = oi; }
            }
            idxsL[tk2] = mi;
        }
        __syncthreads();
    }

    // ---- 6. codes
    if (tid < 64)
        out[OFF_C + (size_t)q * B * T + (size_t)b * T + t0 + tid] = (float)idxsL[tid];

    // ---- 7. faithful f32 straight-through update + loss, 16 tokens at a time:
    //         stage chosen codebook rows coalesced into dead BBUF (padded 257),
    //         then float4-vectorized update over tokens.
    float* rows = resf;   // [16][257]
    double lacc = 0.0;
    #pragma unroll 1
    for (int g = 0; g < 4; ++g) {
        __syncthreads();                         // prev g's reads done
        {
            const int j = tid >> 4, c = tid & 15;
            const float* crow = cbq + (size_t)idxsL[g * 16 + j] * D + c * 16;
            #pragma unroll
            for (int k2 = 0; k2 < 4; ++k2) {
                const float4 v = *(const float4*)(crow + k2 * 4);
                *(float4*)&rows[j * 257 + c * 16 + k2 * 4] = v;
            }
        }
        __syncthreads();
        #pragma unroll
        for (int it = 0; it < 4; ++it) {
            const int tk4 = (tid & 3) * 4;           // token quad within group
            const int dd_ = it * 64 + (tid >> 2);
            const int tk  = g * 16 + tk4;
            const float4 rv = *(const float4*)&rs[(size_t)dd_ * T + tk];
            const float c0 = rows[(tk4 + 0) * 257 + dd_];
            const float c1 = rows[(tk4 + 1) * 257 + dd_];
            const float c2 = rows[(tk4 + 2) * 257 + dd_];
            const float c3 = rows[(tk4 + 3) * 257 + dd_];
            float4 od;
            float e, qst, dv;
            e = c0 - rv.x; qst = rv.x + e; dv = qst - rv.x;
            lacc = fma((double)dv, (double)dv, lacc); od.x = rv.x - qst;
            e = c1 - rv.y; qst = rv.y + e; dv = qst - rv.y;
            lacc = fma((double)dv, (double)dv, lacc); od.y = rv.y - qst;
            e = c2 - rv.z; qst = rv.z + e; dv = qst - rv.z;
            lacc = fma((double)dv, (double)dv, lacc); od.z = rv.z - qst;
            e = c3 - rv.w; qst = rv.w + e; dv = qst - rv.w;
            lacc = fma((double)dv, (double)dv, lacc); od.w = rv.w - qst;
            *(float4*)&rd[(size_t)dd_ * T + tk] = od;
        }
    }

    // ---- 8. deterministic per-block loss partial (wave shuffle + tiny LDS)
    #pragma unroll
    for (int off = 32; off >= 1; off >>= 1)
        lacc += __shfl_xor(lacc, off, 64);
    __syncthreads();
    if (lane == 0) redw[w] = lacc;
    __syncthreads();
    if (tid == 0)
        lpart[(size_t)q * 1024 + bid] = (redw[0] + redw[1]) + (redw[2] + redw[3]);
}

// ---------------- final: quantized = x - res, in place on out[0:B*D*T) ----------
__global__ __launch_bounds__(256) void final_sub(const float* __restrict__ x,
                                                 float* __restrict__ o)
{
    const size_t i = ((size_t)blockIdx.x * 256 + threadIdx.x) * 4;
    const float4v xv = __builtin_nontemporal_load((const float4v*)(x + i));
    const float4v ov = __builtin_nontemporal_load((const float4v*)(o + i));
    const float4v r = xv - ov;
    __builtin_nontemporal_store(r, (float4v*)(o + i));
}

// ---------------- OLD PATH (R2, known-good) kept as ws-size fallback ----------------
#define OTOK 32
#define ORS 260
__global__ __launch_bounds__(256, 3) void rvq_main_old(
    const float* __restrict__ x, const float* __restrict__ cb,
    const double* __restrict__ cbn, const float* __restrict__ cbnf,
    float* __restrict__ out, double* __restrict__ lpart)
{
    __shared__ float  res[OTOK][ORS];
    __shared__ float  bv1s[OTOK][16];
    __shared__ float  bv2s[OTOK][16];
    __shared__ int    bi1s[OTOK][16];
    __shared__ int    idxs[OTOK];
    __shared__ int    flags[OTOK];
    __shared__ double fbv[256];
    __shared__ int    fbi[256];

    const int tid = threadIdx.x;
    const int bid = blockIdx.x;
    const int b  = bid >> 7;
    const int t0 = (bid & 127) * OTOK;

    const float* xb = x + (size_t)b * D * T + t0;
    #pragma unroll
    for (int it = 0; it < 32; ++it) {
        const int d  = it * 8 + (tid >> 5);
        const int tk = tid & 31;
        res[tk][d] = xb[(size_t)d * T + tk];
    }
    __syncthreads();

    float qreg[32];
    #pragma unroll
    for (int i = 0; i < 32; ++i) qreg[i] = 0.0f;

    const int tg = tid & 15;
    const int bg = tid >> 4;
    const int tku = tid >> 3;
    const int d0u = (tid & 7) * 32;
    double lacc = 0.0;

    for (int q = 0; q < NQ; ++q) {
        const float*  cbq = cb   + (size_t)q * BINS * D;
        const float*  cnf = cbnf + (size_t)q * BINS;
        const double* cnd = cbn  + (size_t)q * BINS;

        float bvA = 3.4e38f, bvA2 = 3.4e38f;  int biA = 0;
        float bvB = 3.4e38f, bvB2 = 3.4e38f;  int biB = 0;

        for (int iter = 0; iter < 8; ++iter) {
            const int binbase = iter * 128 + bg * 8;
            float a0[8], a1[8];
            #pragma unroll
            for (int j = 0; j < 8; ++j) { a0[j] = 0.0f; a1[j] = 0.0f; }
            for (int d = 0; d < D; d += 4) {
                const float4 r0 = *(const float4*)&res[tg][d];
                const float4 r1 = *(const float4*)&res[tg + 16][d];
                #pragma unroll
                for (int j = 0; j < 8; ++j) {
                    const float4 c = *(const float4*)&cbq[(size_t)(binbase + j) * D + d];
                    a0[j] = fmaf(r0.x, c.x, a0[j]); a0[j] = fmaf(r0.y, c.y, a0[j]);
                    a0[j] = fmaf(r0.z, c.z, a0[j]); a0[j] = fmaf(r0.w, c.w, a0[j]);
                    a1[j] = fmaf(r1.x, c.x, a1[j]); a1[j] = fmaf(r1.y, c.y, a1[j]);
                    a1[j] = fmaf(r1.z, c.z, a1[j]); a1[j] = fmaf(r1.w, c.w, a1[j]);
                }
            }
            #pragma unroll
            for (int j = 0; j < 8; ++j) {
                const int bin = binbase + j;
                const float qn = cnf[bin];
                const float s0 = fmaf(-2.0f, a0[j], qn);
                const float s1 = fmaf(-2.0f, a1[j], qn);
                if (s0 < bvA) { bvA2 = bvA; bvA = s0; biA = bin; }
                else if (s0 < bvA2) { bvA2 = s0; }
                if (s1 < bvB) { bvB2 = bvB; bvB = s1; biB = bin; }
                else if (s1 < bvB2) { bvB2 = s1; }
            }
        }
        bv1s[tg][bg]      = bvA;  bv2s[tg][bg]      = bvA2;  bi1s[tg][bg]      = biA;
        bv1s[tg + 16][bg] = bvB;  bv2s[tg + 16][bg] = bvB2;  bi1s[tg + 16][bg] = biB;
        __syncthreads();

        if (tid < OTOK) {
            float g1 = bv1s[tid][0], g2 = bv2s[tid][0];
            int   gi = bi1s[tid][0];
            #pragma unroll
            for (int g = 1; g < 16; ++g) {
                const float v1 = bv1s[tid][g];
                const float v2 = bv2s[tid][g];
                const int   i1 = bi1s[tid][g];
                if (v1 < g1 || (v1 == g1 && i1 < gi)) { g2 = fminf(g1, v2); g1 = v1; gi = i1; }
                else g2 = fminf(g2, v1);
            }
            idxs[tid]  = gi;
            flags[tid] = (g2 - g1 < 0.02f) ? 1 : 0;
        }
        __syncthreads();

        for (int tok = 0; tok < OTOK; ++tok) {
            if (!flags[tok]) continue;
            double bb = 1e300; int bbi = 0;
            #pragma unroll
            for (int jj = 0; jj < 4; ++jj) {
                const int bin = tid + 256 * jj;
                const float* crow = cbq + (size_t)bin * D;
                double a = 0.0;
                for (int d = 0; d < D; d += 4) {
                    const float4 r = *(const float4*)&res[tok][d];
                    const float4 c = *(const float4*)&crow[d];
                    a = fma((double)r.x, (double)c.x, a);
                    a = fma((double)r.y, (double)c.y, a);
                    a = fma((double)r.z, (double)c.z, a);
                    a = fma((double)r.w, (double)c.w, a);
                }
                const double s = fma(-2.0, a, cnd[bin]);
                if (s < bb) { bb = s; bbi = bin; }
            }
            fbv[tid] = bb; fbi[tid] = bbi;
            __syncthreads();
            for (int s2 = 128; s2 >= 1; s2 >>= 1) {
                if (tid < s2) {
                    const double ov = fbv[tid + s2]; const int oi = fbi[tid + s2];
                    const double mv = fbv[tid];      const int mi = fbi[tid];
                    if (ov < mv || (ov == mv && oi < mi)) { fbv[tid] = ov; fbi[tid] = oi; }
                }
                __syncthreads();
            }
            if (tid == 0) idxs[tok] = fbi[0];
            __syncthreads();
        }

        if (tid < OTOK)
            out[OFF_C + (size_t)q * B * T + (size_t)b * T + t0 + tid] = (float)idxs[tid];

        const float* crow = cbq + (size_t)idxs[tku] * D;
        #pragma unroll
        for (int i = 0; i < 8; ++i) {
            const int d = d0u + i * 4;
            const float4 qv = *(const float4*)&crow[d];
            float4 r = *(float4*)&res[tku][d];
            float e, qst, dd;
            e = qv.x - r.x; qst = r.x + e; dd = qst - r.x;
            lacc = fma((double)dd, (double)dd, lacc); qreg[i*4+0] += qst; r.x = r.x - qst;
            e = qv.y - r.y; qst = r.y + e; dd = qst - r.y;
            lacc = fma((double)dd, (double)dd, lacc); qreg[i*4+1] += qst; r.y = r.y - qst;
            e = qv.z - r.z; qst = r.z + e; dd = qst - r.z;
            lacc = fma((double)dd, (double)dd, lacc); qreg[i*4+2] += qst; r.z = r.z - qst;
            e = qv.w - r.w; qst = r.w + e; dd = qst - r.w;
            lacc = fma((double)dd, (double)dd, lacc); qreg[i*4+3] += qst; r.w = r.w - qst;
            *(float4*)&res[tku][d] = r;
        }
        __syncthreads();
    }

    #pragma unroll
    for (int i = 0; i < 8; ++i)
        *(float4*)&res[tku][d0u + i * 4] = *(float4*)&qreg[i * 4];
    __syncthreads();
    #pragma unroll
    for (int it = 0; it < 32; ++it) {
        const int d  = it * 8 + (tid >> 5);
        const int tk = tid & 31;
        out[(size_t)b * D * T + (size_t)d * T + t0 + tk] = res[tk][d];
    }

    fbv[tid] = lacc;
    __syncthreads();
    for (int s2 = 128; s2 >= 1; s2 >>= 1) {
        if (tid < s2) fbv[tid] += fbv[tid + s2];
        __syncthreads();
    }
    if (tid == 0) lpart[bid] = fbv[0];
}

// ---------------- finalize: loss mean + bandwidth scalar ----------------
__global__ __launch_bounds__(256) void finalize_kernel(
    const double* __restrict__ lpart, int nblk,
    const int* __restrict__ srp, float* __restrict__ out)
{
    __shared__ double sh[256];
    double a = 0.0;
    for (int i = threadIdx.x; i < nblk; i += 256) a += lpart[i];
    sh[threadIdx.x] = a;
    __syncthreads();
    for (int s = 128; s >= 1; s >>= 1) {
        if (threadIdx.x < s) sh[threadIdx.x] += sh[threadIdx.x + s];
        __syncthreads();
    }
    if (threadIdx.x == 0) {
        out[OFF_L]  = (float)(sh[0] / ((double)NQ * B * T * D));
        out[OFF_BW] = (float)((double)NQ * 10.0 * (double)srp[0] / 1000.0);
    }
}

extern "C" void kernel_launch(void* const* d_in, const int* in_sizes, int n_in,
                              void* d_out, int out_size, void* d_ws, size_t ws_size,
                              hipStream_t stream)
{
    const float* x  = (const float*)d_in[0];
    const float* cb = (const float*)d_in[1];
    const int*   sr = (const int*)d_in[2];
    float* out = (float*)d_out;

    // ws layout: cbn f64[8192] @0 (65536) | cbnf f32[8192] @65536 (32768)
    //            lpart f64[8192] @98304 (65536) | bfh @163840 (4 MiB) | bfl @4358144
    //            total 8552448 B
    double* cbn   = (double*)d_ws;
    float*  cbnf  = (float*)((char*)d_ws + 65536);
    double* lpart = (double*)((char*)d_ws + 98304);
    unsigned short* bfh = (unsigned short*)((char*)d_ws + 163840);
    unsigned short* bfl = (unsigned short*)((char*)d_ws + 4358144);

    hipLaunchKernelGGL(cbnorm_kernel, dim3(NQ * BINS / 4), dim3(256), 0, stream, cb, cbn, cbnf);

    if (ws_size >= (size_t)8552448) {
        hipLaunchKernelGGL(prep_bfrag, dim3(1024), dim3(256), 0, stream, cb, bfh, bfl);
        float* resb = out;   // quantized section doubles as residual buffer
        for (int q = 0; q < NQ; ++q) {
            hipLaunchKernelGGL(rvq_scan, dim3(B * (T / 64)), dim3(256), 0, stream,
                               (q == 0 ? x : (const float*)resb), resb, cb, cbn, cbnf,
                               bfh, bfl, out, lpart, q);
        }
        hipLaunchKernelGGL(final_sub, dim3((B * D * T) / 1024), dim3(256), 0, stream, x, resb);
        hipLaunchKernelGGL(finalize_kernel, dim3(1), dim3(256), 0, stream,
                           lpart, NQ * 1024, sr, out);
    } else {
        hipLaunchKernelGGL(rvq_main_old, dim3(B * (T / OTOK)), dim3(256), 0, stream,
                           x, cb, cbn, cbnf, out, lpart);
        hipLaunchKernelGGL(finalize_kernel, dim3(1), dim3(256), 0, stream,
                           lpart, B * (T / OTOK), sr, out);
    }
}